// Round 1
// baseline (440.081 us; speedup 1.0000x reference)
//
#include <hip/hip_runtime.h>
#include <hip/hip_bf16.h>
#include <cstdint>

typedef __bf16 bf16;
typedef __bf16 bf16x8 __attribute__((ext_vector_type(8)));
typedef float  f32x4  __attribute__((ext_vector_type(4)));

#define B_   2
#define T_   2048
#define D_   2048
#define H_   16
#define HD_  128

// async global->LDS, 16 B per lane (m97: the 874 TF enabler).
// LDS dest must be wave-uniform base + lane*16 -> lanes stay contiguous in
// physical-slot order; we permute the GLOBAL side per-lane for XOR swizzles.
typedef __attribute__((address_space(3))) void       lds_void;
typedef __attribute__((address_space(1))) const void gbl_void;
__device__ __forceinline__ void glds16(const bf16* g, bf16* l) {
    __builtin_amdgcn_global_load_lds((gbl_void*)g, (lds_void*)l, 16, 0, 0);
}

// ---------------------------------------------------------------------------
// fp32 -> bf16 pre-convert (grid-stride, float4 -> 4x bf16 pack)
// ---------------------------------------------------------------------------
__device__ __forceinline__ ushort4 cvt4(const float4 v) {
    union { bf16 h[4]; ushort4 u; } pk;
    pk.h[0] = (bf16)v.x; pk.h[1] = (bf16)v.y;
    pk.h[2] = (bf16)v.z; pk.h[3] = (bf16)v.w;
    return pk.u;
}

__global__ __launch_bounds__(256) void convert_xw_kernel(
    const float* __restrict__ x, const float* __restrict__ wqkv,
    bf16* __restrict__ xb, bf16* __restrict__ wqkvb)
{
    const int NX = (B_ * T_ * D_) / 4;          // 2,097,152 float4
    const int NT = NX + (3 * D_ * D_) / 4;      // + 3,145,728
    for (int g = blockIdx.x * blockDim.x + threadIdx.x; g < NT;
         g += gridDim.x * blockDim.x) {
        if (g < NX) ((ushort4*)xb)[g]      = cvt4(((const float4*)x)[g]);
        else        ((ushort4*)wqkvb)[g-NX] = cvt4(((const float4*)wqkv)[g-NX]);
    }
}

__global__ __launch_bounds__(256) void convert_wo_kernel(
    const float* __restrict__ wo, bf16* __restrict__ wob)
{
    const int N = (D_ * D_) / 4;                // 1,048,576 float4
    for (int g = blockIdx.x * blockDim.x + threadIdx.x; g < N;
         g += gridDim.x * blockDim.x)
        ((ushort4*)wob)[g] = cvt4(((const float4*)wo)[g]);
}

// ---------------------------------------------------------------------------
// m97-style NT-GEMM core with XOR-swizzled LDS: C[128x128], A[M][K], W[N][K]
// bf16 K-major, global_load_lds width-16 staging into [128][64] tiles.
// (unchanged from previous round — 540K conflict cycles, not the bottleneck)
// ---------------------------------------------------------------------------
__device__ __forceinline__ void gemm_core_glds(
    const bf16* __restrict__ A, const bf16* __restrict__ W, int K,
    int bm, int bn, int tid, f32x4 (&acc)[4][4],
    bf16* lds_a, bf16* lds_b)
{
    const int lane = tid & 63, quad = lane >> 4, lcol = lane & 15;
    const int wave = tid >> 6;
    const int wm = (wave >> 1) * 64, wn2 = (wave & 1) * 32;
    const int sw = lcol & 7;                          // read-side swizzle key
    const int sr = tid >> 3, pc = tid & 7;            // staging row / physical chunk
    const int sc = (pc ^ (sr & 7)) * 8;               // logical col group fetched
    const bf16* abase = A + (size_t)(bm * 128 + sr) * K + sc;
    const bf16* bbase = W + (size_t)(bn * 128 + sr) * K + sc;
    bf16* la = lds_a + sr * 64 + pc * 8;              // = lds_a + tid*8 elems
    bf16* lb = lds_b + sr * 64 + pc * 8;

    for (int k0 = 0; k0 < K; k0 += 64) {
        __syncthreads();
#pragma unroll
        for (int p = 0; p < 4; p++) {                 // (sr+32p)&7 == sr&7
            glds16(abase + k0 + (size_t)32 * p * K, la + 2048 * p);
            glds16(bbase + k0 + (size_t)32 * p * K, lb + 2048 * p);
        }
        __syncthreads();
#pragma unroll
        for (int kk = 0; kk < 2; kk++) {
            bf16x8 af[4], bfr[4];
#pragma unroll
            for (int i = 0; i < 4; i++)
                af[i] = *(const bf16x8*)&lds_a[(wm + i * 16 + lcol) * 64 +
                                               (((kk * 4 + quad) ^ sw) * 8)];
#pragma unroll
            for (int j = 0; j < 4; j++) {
                const int row = wn2 + (j & 1) * 16 + (j >> 1) * 64 + lcol;
                bfr[j] = *(const bf16x8*)&lds_b[row * 64 +
                                                (((kk * 4 + quad) ^ sw) * 8)];
            }
#pragma unroll
            for (int i = 0; i < 4; i++)
#pragma unroll
                for (int j = 0; j < 4; j++)
                    acc[i][j] = __builtin_amdgcn_mfma_f32_16x16x32_bf16(af[i], bfr[j], acc[i][j], 0, 0, 0);
        }
    }
}

// ---------------------------------------------------------------------------
// QKV projection (bf16 in via pre-convert) + fused RoPE + head scatter:
//   q,k -> [bh][t][d] with rotary applied;  v -> vT[bh][d][t]
// R6: vT keys are PI-PERMUTED within each 64-t block:
//   phys(t) = (t&15)*4 + (t>>4)
// This makes attn's P-store a packed ushort4 (4 contiguous phys keys per
// thread) while V-fragment reads stay bf16x8-contiguous.  The thread's acc
// holds t = i*16 + quad*4 + r, so phys = (quad*4+r)*4 + i -> pack across i.
// ---------------------------------------------------------------------------
__global__ __launch_bounds__(256) void qkv_gemm_kernel(
    const bf16* __restrict__ xb, const bf16* __restrict__ wqkvb,
    const float* __restrict__ bias,
    bf16* __restrict__ qh, bf16* __restrict__ kh, bf16* __restrict__ vT)
{
    __shared__ bf16 lds_a[128 * 64];
    __shared__ bf16 lds_b[128 * 64];
    const int tid = threadIdx.x;
    const int bm = blockIdx.y, bn = blockIdx.x;
    const int lane = tid & 63, quad = lane >> 4, lcol = lane & 15;
    const int wave = tid >> 6;
    const int wm = (wave >> 1) * 64, wn2 = (wave & 1) * 32;

    f32x4 acc[4][4];
    const f32x4 z = {0.f, 0.f, 0.f, 0.f};
#pragma unroll
    for (int i = 0; i < 4; i++)
#pragma unroll
        for (int j = 0; j < 4; j++) acc[i][j] = z;

    gemm_core_glds(xb, wqkvb, D_, bm, bn, tid, acc, lds_a, lds_b);

    const int n0 = bn * 128;
    const int part = bn / 16;            // 0=q 1=k 2=v (block-uniform)
    const int h = bn & 15;
    const int mb0 = bm * 128 + wm;       // 64-aligned -> one batch, one 64-blk

    if (part < 2) {
        bf16* dst = (part == 0) ? qh : kh;
#pragma unroll
        for (int i = 0; i < 4; i++) {
#pragma unroll
            for (int jp = 0; jp < 2; jp++) {
                const int d1 = wn2 + jp * 16 + lcol;       // 0..63
                const float invf = __expf(-0.14391156831212787f * (float)d1);
                const float b1 = bias[n0 + d1];
                const float b2 = bias[n0 + d1 + 64];
#pragma unroll
                for (int r = 0; r < 4; r++) {
                    const int m = mb0 + i * 16 + quad * 4 + r;
                    const int bb = m >> 11, t = m & (T_ - 1);
                    const float x1 = acc[i][jp][r] + b1;       // d1
                    const float x2 = acc[i][jp + 2][r] + b2;   // d1 + 64
                    float s, c;
                    __sincosf((float)t * invf, &s, &c);
                    const size_t rowo = ((size_t)(bb * H_ + h) * T_ + t) * HD_;
                    dst[rowo + d1]      = (bf16)(x1 * c - x2 * s);
                    dst[rowo + d1 + 64] = (bf16)(x1 * s + x2 * c);
                }
            }
        }
    } else {
        const int bb = mb0 >> 11, t64 = mb0 & (T_ - 1);   // 64-aligned t base
        const int bh = bb * H_ + h;
#pragma unroll
        for (int j = 0; j < 4; j++) {
            const int d = wn2 + (j & 1) * 16 + (j >> 1) * 64 + lcol;
            const float bv = bias[n0 + d];
            bf16* vdst = &vT[((size_t)bh * HD_ + d) * T_ + t64];
#pragma unroll
            for (int r = 0; r < 4; r++) {
                union { bf16 hh[4]; ushort4 u; } pk;
#pragma unroll
                for (int i = 0; i < 4; i++) pk.hh[i] = (bf16)(acc[i][j][r] + bv);
                // phys(t=i*16+quad*4+r) = (quad*4+r)*4 + i  -> contiguous in i
                *(ushort4*)&vdst[(quad * 4 + r) * 4] = pk.u;
            }
        }
    }
}

// ---------------------------------------------------------------------------
// Flash attention (causal), R6 restructure for OCCUPANCY (was 10.7%):
//  * 16 q-rows/wave (was 32) -> 1024 blocks of 64 q-rows -> 4 blocks/CU,
//    __launch_bounds__(256,4) caps VGPR at 128 -> 16 waves/CU (was 8).
//  * K tile (64x128) double-buffered in LDS via global_load_lds, shared by
//    all 4 waves (block-uniform ktmax: one barrier/tile, kt+1 prefetch
//    issued right after the barrier -> full tile of compute hides it).
//    Bank-conflict-free: col ^= (row&15)<<4 byte swizzle, applied by
//    pre-swizzling the GLOBAL source address (m173), linear LDS dest.
//  * P keys pi-permuted (matches vT producer): P-store = 4x ushort4
//    (was 32x scalar ds_write_b16); V reads need no unpermute.
//  * V stays direct-from-global: splits K/V read volume across the LDS and
//    L2 pipes instead of doubling one of them.
//  * No-max softmax kept: p = exp2(s*scale*log2e - 16), exact-pow2 shift
//    cancels in o/l; causal mask only on the diagonal tile.
// LDS: 2*16KB (K dbuf) + 8KB (P) = 40960 B -> exactly 4 blocks/CU.
// ---------------------------------------------------------------------------
__global__ __launch_bounds__(256, 4) void attn_kernel(
    const bf16* __restrict__ qh, const bf16* __restrict__ kh,
    const bf16* __restrict__ vT, bf16* __restrict__ ctx)
{
    __shared__ bf16 lds_k[2][64 * 128];   // XOR-swizzled K tiles
    __shared__ bf16 lds_p[64 * 64];       // P (phys-key order), wave-private rows
    const int tid = threadIdx.x;
    const int id = blockIdx.x;            // 1024 = 32 bh x 32 q-tiles
    const int bh = id & 31;
    const int q5 = (id >> 5) & 15;
    const int qt = (id >> 9) ? (31 - q5) : q5;   // high/low pairing for balance
    const int q0 = qt * 64;
    const int lane = tid & 63, quad = lane >> 4, lcol = lane & 15;
    const int wave = tid >> 6;
    const int wq0 = wave * 16;
    const float scale2 = 0.08838834764831845f * 1.4426950408889634f;

    const bf16* kbase = kh + (size_t)bh * T_ * HD_;
    const bf16* vbase = vT + (size_t)bh * HD_ * T_;

    // K staging: thread fills LDS slot tid*16B (+p*4KB); global row srow+p*16,
    // global col pre-swizzled so LDS[row][c] = K[row][c ^ ((row&15)*8)]
    const int srow = tid >> 4;                       // 0..15
    const int scol = ((tid & 15) ^ srow) << 3;       // elems
    const bf16* kstage = kbase + (size_t)srow * HD_ + scol;

    // Q fragments in registers (A-operand layout, straight from global)
    bf16x8 qf[4];
#pragma unroll
    for (int kk = 0; kk < 4; kk++)
        qf[kk] = *(const bf16x8*)&qh[((size_t)bh * T_ + q0 + wq0 + lcol) * HD_ +
                                     kk * 32 + quad * 8];

    f32x4 o[8];
    const f32x4 z = {0.f, 0.f, 0.f, 0.f};
#pragma unroll
    for (int jd = 0; jd < 8; jd++) o[jd] = z;
    float l_part[4] = {0.f, 0.f, 0.f, 0.f};

    const int ktmax = qt + 1;             // block-uniform: 64-row q block
    // prologue: stage K tile 0 into buf 0
#pragma unroll
    for (int p = 0; p < 4; p++)
        glds16(kstage + (size_t)p * 16 * HD_, &lds_k[0][tid * 8 + p * 2048]);

    for (int kt = 0; kt < ktmax; kt++) {
        __syncthreads();                  // stage(kt) landed; buf^1 reads done
        if (kt + 1 < ktmax) {             // prefetch kt+1 (block-uniform branch)
            const bf16* ks = kstage + (size_t)(kt + 1) * 64 * HD_;
#pragma unroll
            for (int p = 0; p < 4; p++)
                glds16(ks + (size_t)p * 16 * HD_,
                       &lds_k[(kt + 1) & 1][tid * 8 + p * 2048]);
        }
        const bf16* lk = lds_k[kt & 1];

        // ---- QK^T: K B-fragments from swizzled LDS ----
        f32x4 s_acc[4];
#pragma unroll
        for (int j = 0; j < 4; j++) s_acc[j] = z;
        __builtin_amdgcn_s_setprio(1);
#pragma unroll
        for (int kk = 0; kk < 4; kk++) {
#pragma unroll
            for (int j = 0; j < 4; j++) {
                const bf16x8 bk = *(const bf16x8*)&lk[(j * 16 + lcol) * 128 +
                                        (((kk * 4 + quad) ^ lcol) << 3)];
                s_acc[j] = __builtin_amdgcn_mfma_f32_16x16x32_bf16(qf[kk], bk, s_acc[j], 0, 0, 0);
            }
        }
        __builtin_amdgcn_s_setprio(0);

        // ---- no-max softmax; packed P store in pi-permuted key order ----
        const bool diag = (kt == qt);
#pragma unroll
        for (int r = 0; r < 4; r++) {
            const int prow = wq0 + quad * 4 + r;      // P row (q-local)
            const int qrow = q0 + prow;               // global q row
            union { bf16 hh[4]; ushort4 u; } pk;
            float lp = 0.f;
#pragma unroll
            for (int j = 0; j < 4; j++) {
                float p = exp2f(fmaf(s_acc[j][r], scale2, -16.0f));
                if (diag) {
                    const int kcol = kt * 64 + j * 16 + lcol;
                    p = (kcol > qrow) ? 0.f : p;
                }
                lp += p;
                pk.hh[j] = (bf16)p;      // phys key = lcol*4 + j
            }
            l_part[r] += lp;
            *(ushort4*)&lds_p[prow * 64 + ((lcol * 4) ^ ((prow & 7) << 3))] = pk.u;
        }

        // ---- PV: P from wave-private LDS, V B-fragments direct from global
        //      (vT is pre-permuted -> phys order is load order) ----
        const bf16* vrow = vbase + kt * 64 + quad * 8;
#pragma unroll
        for (int kk2 = 0; kk2 < 2; kk2++) {
            const int prow = wq0 + lcol;
            const bf16x8 pf = *(const bf16x8*)&lds_p[prow * 64 +
                                  ((kk2 * 32 + quad * 8) ^ ((lcol & 7) << 3))];
            bf16x8 vf[8];
#pragma unroll
            for (int jd = 0; jd < 8; jd++)
                vf[jd] = *(const bf16x8*)&vrow[(size_t)(jd * 16 + lcol) * T_ + kk2 * 32];
            __builtin_amdgcn_s_setprio(1);
#pragma unroll
            for (int jd = 0; jd < 8; jd++)
                o[jd] = __builtin_amdgcn_mfma_f32_16x16x32_bf16(pf, vf[jd], o[jd], 0, 0, 0);
            __builtin_amdgcn_s_setprio(0);
        }
    }

    // final l reduction: 16 lanes of the quad hold partials of the same q-row
    float inv_l[4];
#pragma unroll
    for (int r = 0; r < 4; r++) {
        float rs = l_part[r];
#pragma unroll
        for (int off = 1; off < 16; off <<= 1)
            rs += __shfl_xor(rs, off);
        inv_l[r] = 1.0f / rs;
    }
    // epilogue: ctx[(b*T + t)][h*HD + d], row-major D for the proj GEMM
    const int b = bh >> 4, h = bh & 15;
#pragma unroll
    for (int r = 0; r < 4; r++) {
        const int t = q0 + wq0 + quad * 4 + r;
#pragma unroll
        for (int jd = 0; jd < 8; jd++)
            ctx[((size_t)(b * T_ + t)) * D_ + h * HD_ + jd * 16 + lcol] =
                (bf16)(o[jd][r] * inv_l[r]);
    }
}

// ---------------------------------------------------------------------------
// Output projection: out = ctx @ Wo^T + bo  (bf16 x bf16 -> fp32 out)
// ---------------------------------------------------------------------------
__global__ __launch_bounds__(256) void proj_gemm_kernel(
    const bf16* __restrict__ ctx, const bf16* __restrict__ wob,
    const float* __restrict__ bias, float* __restrict__ out)
{
    __shared__ bf16 lds_a[128 * 64];
    __shared__ bf16 lds_b[128 * 64];
    const int tid = threadIdx.x;
    const int bm = blockIdx.y, bn = blockIdx.x;
    const int lane = tid & 63, quad = lane >> 4, lcol = lane & 15;
    const int wave = tid >> 6;
    const int wm = (wave >> 1) * 64, wn2 = (wave & 1) * 32;

    f32x4 acc[4][4];
    const f32x4 z = {0.f, 0.f, 0.f, 0.f};
#pragma unroll
    for (int i = 0; i < 4; i++)
#pragma unroll
        for (int j = 0; j < 4; j++) acc[i][j] = z;

    gemm_core_glds(ctx, wob, D_, bm, bn, tid, acc, lds_a, lds_b);

    const int n0 = bn * 128;
#pragma unroll
    for (int i = 0; i < 4; i++) {
#pragma unroll
        for (int j = 0; j < 4; j++) {
            const int n = n0 + wn2 + (j & 1) * 16 + (j >> 1) * 64 + lcol;
            const float bv = bias[n];
#pragma unroll
            for (int r = 0; r < 4; r++) {
                const int m = bm * 128 + wm + i * 16 + quad * 4 + r;
                out[(size_t)m * D_ + n] = acc[i][j][r] + bv;
            }
        }
    }
}

extern "C" void kernel_launch(void* const* d_in, const int* in_sizes, int n_in,
                              void* d_out, int out_size, void* d_ws, size_t ws_size,
                              hipStream_t stream)
{
    const float* x    = (const float*)d_in[0];
    const float* Wqkv = (const float*)d_in[1];
    const float* bqkv = (const float*)d_in[2];
    const float* Wo   = (const float*)d_in[3];
    const float* bo   = (const float*)d_in[4];
    // d_in[5] = mask — causal, computed analytically in-kernel.
    float* out = (float*)d_out;

    const size_t HT = (size_t)B_ * H_ * T_ * HD_;   // 8,388,608 elems
    // d_ws (67.1 MB, proven size): [xb|ctx][qh|wob][kh][vT]
    bf16* xb   = (bf16*)d_ws;
    bf16* qh   = xb + HT;
    bf16* kh   = qh + HT;
    bf16* vT   = kh + HT;
    bf16* ctx  = xb;             // xb dead after qkv gemm
    bf16* wob  = qh;             // qh dead after attn
    // d_out (33.55 MB fp32): holds bf16 Wqkv (25.2 MB) until proj overwrites
    bf16* wqkvb = (bf16*)d_out;

    // 1) fp32 -> bf16 pre-convert of x and Wqkv
    convert_xw_kernel<<<2560, 256, 0, stream>>>(x, Wqkv, xb, wqkvb);
    // 2) QKV projection + fused RoPE + head scatter (vT pi-permuted keys)
    qkv_gemm_kernel<<<dim3(48, 32), 256, 0, stream>>>(xb, wqkvb, bqkv, qh, kh, vT);
    // 3) causal flash attention -> ctx: 1024 blocks (64 q-rows each),
    //    K dbuf in LDS, 4 blocks/CU, 16 waves/CU
    attn_kernel<<<1024, 256, 0, stream>>>(qh, kh, vT, ctx);
    // 4) Wo -> bf16 into dead qh region
    convert_wo_kernel<<<1024, 256, 0, stream>>>(Wo, wob);
    // 5) output projection -> fp32 out (overwrites wqkvb region)
    proj_gemm_kernel<<<dim3(16, 32), 256, 0, stream>>>(ctx, wob, bo, out);
}

// Round 2
// 351.618 us; speedup vs baseline: 1.2516x; 1.2516x over previous
//
#include <hip/hip_runtime.h>
#include <hip/hip_bf16.h>
#include <cstdint>

typedef __bf16 bf16;
typedef __bf16 bf16x8 __attribute__((ext_vector_type(8)));
typedef float  f32x4  __attribute__((ext_vector_type(4)));

#define B_   2
#define T_   2048
#define D_   2048
#define H_   16
#define HD_  128

// async global->LDS, 16 B per lane (m97: the 874 TF enabler).
// LDS dest must be wave-uniform base + lane*16 -> lanes stay contiguous in
// physical-slot order; we permute the GLOBAL side per-lane for XOR swizzles.
typedef __attribute__((address_space(3))) void       lds_void;
typedef __attribute__((address_space(1))) const void gbl_void;
__device__ __forceinline__ void glds16(const bf16* g, bf16* l) {
    __builtin_amdgcn_global_load_lds((gbl_void*)g, (lds_void*)l, 16, 0, 0);
}

// ---------------------------------------------------------------------------
// fp32 -> bf16 pre-convert (grid-stride, float4 -> 4x bf16 pack)
// ---------------------------------------------------------------------------
__device__ __forceinline__ ushort4 cvt4(const float4 v) {
    union { bf16 h[4]; ushort4 u; } pk;
    pk.h[0] = (bf16)v.x; pk.h[1] = (bf16)v.y;
    pk.h[2] = (bf16)v.z; pk.h[3] = (bf16)v.w;
    return pk.u;
}

__global__ __launch_bounds__(256) void convert_xw_kernel(
    const float* __restrict__ x, const float* __restrict__ wqkv,
    bf16* __restrict__ xb, bf16* __restrict__ wqkvb)
{
    const int NX = (B_ * T_ * D_) / 4;          // 2,097,152 float4
    const int NT = NX + (3 * D_ * D_) / 4;      // + 3,145,728
    for (int g = blockIdx.x * blockDim.x + threadIdx.x; g < NT;
         g += gridDim.x * blockDim.x) {
        if (g < NX) ((ushort4*)xb)[g]      = cvt4(((const float4*)x)[g]);
        else        ((ushort4*)wqkvb)[g-NX] = cvt4(((const float4*)wqkv)[g-NX]);
    }
}

__global__ __launch_bounds__(256) void convert_wo_kernel(
    const float* __restrict__ wo, bf16* __restrict__ wob)
{
    const int N = (D_ * D_) / 4;                // 1,048,576 float4
    for (int g = blockIdx.x * blockDim.x + threadIdx.x; g < N;
         g += gridDim.x * blockDim.x)
        ((ushort4*)wob)[g] = cvt4(((const float4*)wo)[g]);
}

// ---------------------------------------------------------------------------
// m97-style NT-GEMM core with XOR-swizzled LDS: C[128x128], A[M][K], W[N][K]
// bf16 K-major, global_load_lds width-16 staging into [128][64] tiles.
// ---------------------------------------------------------------------------
__device__ __forceinline__ void gemm_core_glds(
    const bf16* __restrict__ A, const bf16* __restrict__ W, int K,
    int bm, int bn, int tid, f32x4 (&acc)[4][4],
    bf16* lds_a, bf16* lds_b)
{
    const int lane = tid & 63, quad = lane >> 4, lcol = lane & 15;
    const int wave = tid >> 6;
    const int wm = (wave >> 1) * 64, wn2 = (wave & 1) * 32;
    const int sw = lcol & 7;                          // read-side swizzle key
    const int sr = tid >> 3, pc = tid & 7;            // staging row / physical chunk
    const int sc = (pc ^ (sr & 7)) * 8;               // logical col group fetched
    const bf16* abase = A + (size_t)(bm * 128 + sr) * K + sc;
    const bf16* bbase = W + (size_t)(bn * 128 + sr) * K + sc;
    bf16* la = lds_a + sr * 64 + pc * 8;              // = lds_a + tid*8 elems
    bf16* lb = lds_b + sr * 64 + pc * 8;

    for (int k0 = 0; k0 < K; k0 += 64) {
        __syncthreads();
#pragma unroll
        for (int p = 0; p < 4; p++) {                 // (sr+32p)&7 == sr&7
            glds16(abase + k0 + (size_t)32 * p * K, la + 2048 * p);
            glds16(bbase + k0 + (size_t)32 * p * K, lb + 2048 * p);
        }
        __syncthreads();
#pragma unroll
        for (int kk = 0; kk < 2; kk++) {
            bf16x8 af[4], bfr[4];
#pragma unroll
            for (int i = 0; i < 4; i++)
                af[i] = *(const bf16x8*)&lds_a[(wm + i * 16 + lcol) * 64 +
                                               (((kk * 4 + quad) ^ sw) * 8)];
#pragma unroll
            for (int j = 0; j < 4; j++) {
                const int row = wn2 + (j & 1) * 16 + (j >> 1) * 64 + lcol;
                bfr[j] = *(const bf16x8*)&lds_b[row * 64 +
                                                (((kk * 4 + quad) ^ sw) * 8)];
            }
#pragma unroll
            for (int i = 0; i < 4; i++)
#pragma unroll
                for (int j = 0; j < 4; j++)
                    acc[i][j] = __builtin_amdgcn_mfma_f32_16x16x32_bf16(af[i], bfr[j], acc[i][j], 0, 0, 0);
        }
    }
}

// ---------------------------------------------------------------------------
// QKV projection (bf16 in via pre-convert) + fused RoPE + head scatter:
//   q,k -> [bh][t][d] with rotary applied;  v -> vT[bh][d][t]
// vT keys are PI-PERMUTED within each 64-t block: phys(t) = (t&15)*4 + (t>>4)
// -> attn's P-store is a packed ushort4 and V reads stay bf16x8-contiguous.
// ---------------------------------------------------------------------------
__global__ __launch_bounds__(256) void qkv_gemm_kernel(
    const bf16* __restrict__ xb, const bf16* __restrict__ wqkvb,
    const float* __restrict__ bias,
    bf16* __restrict__ qh, bf16* __restrict__ kh, bf16* __restrict__ vT)
{
    __shared__ bf16 lds_a[128 * 64];
    __shared__ bf16 lds_b[128 * 64];
    const int tid = threadIdx.x;
    const int bm = blockIdx.y, bn = blockIdx.x;
    const int lane = tid & 63, quad = lane >> 4, lcol = lane & 15;
    const int wave = tid >> 6;
    const int wm = (wave >> 1) * 64, wn2 = (wave & 1) * 32;

    f32x4 acc[4][4];
    const f32x4 z = {0.f, 0.f, 0.f, 0.f};
#pragma unroll
    for (int i = 0; i < 4; i++)
#pragma unroll
        for (int j = 0; j < 4; j++) acc[i][j] = z;

    gemm_core_glds(xb, wqkvb, D_, bm, bn, tid, acc, lds_a, lds_b);

    const int n0 = bn * 128;
    const int part = bn / 16;            // 0=q 1=k 2=v (block-uniform)
    const int h = bn & 15;
    const int mb0 = bm * 128 + wm;       // 64-aligned -> one batch, one 64-blk

    if (part < 2) {
        bf16* dst = (part == 0) ? qh : kh;
#pragma unroll
        for (int i = 0; i < 4; i++) {
#pragma unroll
            for (int jp = 0; jp < 2; jp++) {
                const int d1 = wn2 + jp * 16 + lcol;       // 0..63
                const float invf = __expf(-0.14391156831212787f * (float)d1);
                const float b1 = bias[n0 + d1];
                const float b2 = bias[n0 + d1 + 64];
#pragma unroll
                for (int r = 0; r < 4; r++) {
                    const int m = mb0 + i * 16 + quad * 4 + r;
                    const int bb = m >> 11, t = m & (T_ - 1);
                    const float x1 = acc[i][jp][r] + b1;       // d1
                    const float x2 = acc[i][jp + 2][r] + b2;   // d1 + 64
                    float s, c;
                    __sincosf((float)t * invf, &s, &c);
                    const size_t rowo = ((size_t)(bb * H_ + h) * T_ + t) * HD_;
                    dst[rowo + d1]      = (bf16)(x1 * c - x2 * s);
                    dst[rowo + d1 + 64] = (bf16)(x1 * s + x2 * c);
                }
            }
        }
    } else {
        const int bb = mb0 >> 11, t64 = mb0 & (T_ - 1);   // 64-aligned t base
        const int bh = bb * H_ + h;
#pragma unroll
        for (int j = 0; j < 4; j++) {
            const int d = wn2 + (j & 1) * 16 + (j >> 1) * 64 + lcol;
            const float bv = bias[n0 + d];
            bf16* vdst = &vT[((size_t)bh * HD_ + d) * T_ + t64];
#pragma unroll
            for (int r = 0; r < 4; r++) {
                union { bf16 hh[4]; ushort4 u; } pk;
#pragma unroll
                for (int i = 0; i < 4; i++) pk.hh[i] = (bf16)(acc[i][j][r] + bv);
                // phys(t=i*16+quad*4+r) = (quad*4+r)*4 + i  -> contiguous in i
                *(ushort4*)&vdst[(quad * 4 + r) * 4] = pk.u;
            }
        }
    }
}

// ---------------------------------------------------------------------------
// Flash attention (causal), R7:
// R6 post-mortem: launch_bounds(256,4) VGPR cap (count=64) caused scratch
// spills (+12MB WRITE, +6MB FETCH) and blocked V-load hoisting -> per-tile
// serial global-latency stall, all waves barrier-locked together.
// R7 fixes:
//  * no VGPR cap (launch_bounds(256)) -> no spills.
//  * V tile ALSO staged in LDS (dbuf, glds width-16, global-side XOR
//    swizzle): PV operands become LDS-latency; prefetch of tile kt+1 issued
//    at top of tile kt overlaps the whole tile's compute (m97 schedule).
//    Also cuts V cache traffic 4x (read per block-tile, not per wave-tile).
//  * keeps: 64-row q blocks, grid 1024, K-LDS swizzle, pi-permuted packed P,
//    no-max softmax (p = exp2(s*scale*log2e - 16), shift cancels in o/l),
//    diag-only masking, setprio around MFMA clusters.
// LDS: 2*16KB (K) + 2*16KB (V) + 8KB (P) = 72KB -> 2 blocks/CU, 8 waves/CU.
// ---------------------------------------------------------------------------
__global__ __launch_bounds__(256) void attn_kernel(
    const bf16* __restrict__ qh, const bf16* __restrict__ kh,
    const bf16* __restrict__ vT, bf16* __restrict__ ctx)
{
    __shared__ bf16 lds_k[2][64 * 128];   // [key][d], XOR-swizzled
    __shared__ bf16 lds_v[2][128 * 64];   // [d][phys-key], XOR-swizzled
    __shared__ bf16 lds_p[64 * 64];       // P (phys-key order), wave-private rows
    const int tid = threadIdx.x;
    const int id = blockIdx.x;            // 1024 = 32 bh x 32 q-tiles
    const int bh = id & 31;
    const int q5 = (id >> 5) & 15;
    const int qt = (id >> 9) ? (31 - q5) : q5;   // light half then heavy half
    const int q0 = qt * 64;
    const int lane = tid & 63, quad = lane >> 4, lcol = lane & 15;
    const int wave = tid >> 6;
    const int wq0 = wave * 16;
    const float scale2 = 0.08838834764831845f * 1.4426950408889634f;

    const bf16* kbase = kh + (size_t)bh * T_ * HD_;
    const bf16* vbase = vT + (size_t)bh * HD_ * T_;

    // K staging: row srow+16p, chunk tid&15; src col chunk ^ (row&15).
    const int ksrow = tid >> 4;                        // 0..15
    const bf16* kstage = kbase + (size_t)ksrow * HD_ + (((tid & 15) ^ ksrow) << 3);
    // V staging: d row vsd+32p, chunk tid&7; src key chunk ^ (d&7).
    const int vsd = tid >> 3;                          // 0..31
    const bf16* vstage = vbase + (size_t)vsd * T_ + (((tid & 7) ^ (vsd & 7)) << 3);

    // Q fragments in registers (A-operand layout, straight from global)
    bf16x8 qf[4];
#pragma unroll
    for (int kk = 0; kk < 4; kk++)
        qf[kk] = *(const bf16x8*)&qh[((size_t)bh * T_ + q0 + wq0 + lcol) * HD_ +
                                     kk * 32 + quad * 8];

    f32x4 o[8];
    const f32x4 z = {0.f, 0.f, 0.f, 0.f};
#pragma unroll
    for (int jd = 0; jd < 8; jd++) o[jd] = z;
    float l_part[4] = {0.f, 0.f, 0.f, 0.f};

    const int ktmax = qt + 1;             // block-uniform
    // prologue: stage tile 0 into buf 0
#pragma unroll
    for (int p = 0; p < 4; p++) {
        glds16(kstage + (size_t)16 * p * HD_, &lds_k[0][tid * 8 + p * 2048]);
        glds16(vstage + (size_t)32 * p * T_, &lds_v[0][tid * 8 + p * 2048]);
    }

    for (int kt = 0; kt < ktmax; kt++) {
        __syncthreads();                  // stage(kt) landed; buf^1 reads done
        if (kt + 1 < ktmax) {             // prefetch kt+1 (block-uniform)
            const bf16* ks = kstage + (size_t)(kt + 1) * 64 * HD_;
            const bf16* vs = vstage + (kt + 1) * 64;
            bf16* lkd = &lds_k[(kt + 1) & 1][tid * 8];
            bf16* lvd = &lds_v[(kt + 1) & 1][tid * 8];
#pragma unroll
            for (int p = 0; p < 4; p++) {
                glds16(ks + (size_t)16 * p * HD_, lkd + p * 2048);
                glds16(vs + (size_t)32 * p * T_, lvd + p * 2048);
            }
        }
        const bf16* lk = lds_k[kt & 1];
        const bf16* lv = lds_v[kt & 1];

        // ---- QK^T: K B-fragments from swizzled LDS ----
        f32x4 s_acc[4];
#pragma unroll
        for (int j = 0; j < 4; j++) s_acc[j] = z;
        __builtin_amdgcn_s_setprio(1);
#pragma unroll
        for (int kk = 0; kk < 4; kk++) {
#pragma unroll
            for (int j = 0; j < 4; j++) {
                const bf16x8 bk = *(const bf16x8*)&lk[(j * 16 + lcol) * 128 +
                                        (((kk * 4 + quad) ^ lcol) << 3)];
                s_acc[j] = __builtin_amdgcn_mfma_f32_16x16x32_bf16(qf[kk], bk, s_acc[j], 0, 0, 0);
            }
        }
        __builtin_amdgcn_s_setprio(0);

        // ---- no-max softmax; packed P store in pi-permuted key order ----
        const bool diag = (kt == qt);
#pragma unroll
        for (int r = 0; r < 4; r++) {
            const int prow = wq0 + quad * 4 + r;      // P row (q-local)
            const int qrow = q0 + prow;               // global q row
            union { bf16 hh[4]; ushort4 u; } pk;
            float lp = 0.f;
#pragma unroll
            for (int j = 0; j < 4; j++) {
                float p = exp2f(fmaf(s_acc[j][r], scale2, -16.0f));
                if (diag) {
                    const int kcol = kt * 64 + j * 16 + lcol;
                    p = (kcol > qrow) ? 0.f : p;
                }
                lp += p;
                pk.hh[j] = (bf16)p;      // phys key = lcol*4 + j
            }
            l_part[r] += lp;
            *(ushort4*)&lds_p[prow * 64 + ((lcol * 4) ^ ((prow & 7) << 3))] = pk.u;
        }

        // ---- PV: P and V both from LDS (short, stall-free path) ----
#pragma unroll
        for (int kk2 = 0; kk2 < 2; kk2++) {
            const int prow = wq0 + lcol;
            const bf16x8 pf = *(const bf16x8*)&lds_p[prow * 64 +
                                  ((kk2 * 32 + quad * 8) ^ ((lcol & 7) << 3))];
            bf16x8 vf[8];
#pragma unroll
            for (int jd = 0; jd < 8; jd++) {
                const int d = jd * 16 + lcol;
                vf[jd] = *(const bf16x8*)&lv[d * 64 +
                              (((kk2 * 4 + quad) ^ (lcol & 7)) << 3)];
            }
            __builtin_amdgcn_s_setprio(1);
#pragma unroll
            for (int jd = 0; jd < 8; jd++)
                o[jd] = __builtin_amdgcn_mfma_f32_16x16x32_bf16(pf, vf[jd], o[jd], 0, 0, 0);
            __builtin_amdgcn_s_setprio(0);
        }
    }

    // final l reduction: 16 lanes of the quad hold partials of the same q-row
    float inv_l[4];
#pragma unroll
    for (int r = 0; r < 4; r++) {
        float rs = l_part[r];
#pragma unroll
        for (int off = 1; off < 16; off <<= 1)
            rs += __shfl_xor(rs, off);
        inv_l[r] = 1.0f / rs;
    }
    // epilogue: ctx[(b*T + t)][h*HD + d], row-major D for the proj GEMM
    const int b = bh >> 4, h = bh & 15;
#pragma unroll
    for (int r = 0; r < 4; r++) {
        const int t = q0 + wq0 + quad * 4 + r;
#pragma unroll
        for (int jd = 0; jd < 8; jd++)
            ctx[((size_t)(b * T_ + t)) * D_ + h * HD_ + jd * 16 + lcol] =
                (bf16)(o[jd][r] * inv_l[r]);
    }
}

// ---------------------------------------------------------------------------
// Output projection: out = ctx @ Wo^T + bo  (bf16 x bf16 -> fp32 out)
// ---------------------------------------------------------------------------
__global__ __launch_bounds__(256) void proj_gemm_kernel(
    const bf16* __restrict__ ctx, const bf16* __restrict__ wob,
    const float* __restrict__ bias, float* __restrict__ out)
{
    __shared__ bf16 lds_a[128 * 64];
    __shared__ bf16 lds_b[128 * 64];
    const int tid = threadIdx.x;
    const int bm = blockIdx.y, bn = blockIdx.x;
    const int lane = tid & 63, quad = lane >> 4, lcol = lane & 15;
    const int wave = tid >> 6;
    const int wm = (wave >> 1) * 64, wn2 = (wave & 1) * 32;

    f32x4 acc[4][4];
    const f32x4 z = {0.f, 0.f, 0.f, 0.f};
#pragma unroll
    for (int i = 0; i < 4; i++)
#pragma unroll
        for (int j = 0; j < 4; j++) acc[i][j] = z;

    gemm_core_glds(ctx, wob, D_, bm, bn, tid, acc, lds_a, lds_b);

    const int n0 = bn * 128;
#pragma unroll
    for (int i = 0; i < 4; i++) {
#pragma unroll
        for (int j = 0; j < 4; j++) {
            const int n = n0 + wn2 + (j & 1) * 16 + (j >> 1) * 64 + lcol;
            const float bv = bias[n];
#pragma unroll
            for (int r = 0; r < 4; r++) {
                const int m = bm * 128 + wm + i * 16 + quad * 4 + r;
                out[(size_t)m * D_ + n] = acc[i][j][r] + bv;
            }
        }
    }
}

extern "C" void kernel_launch(void* const* d_in, const int* in_sizes, int n_in,
                              void* d_out, int out_size, void* d_ws, size_t ws_size,
                              hipStream_t stream)
{
    const float* x    = (const float*)d_in[0];
    const float* Wqkv = (const float*)d_in[1];
    const float* bqkv = (const float*)d_in[2];
    const float* Wo   = (const float*)d_in[3];
    const float* bo   = (const float*)d_in[4];
    // d_in[5] = mask — causal, computed analytically in-kernel.
    float* out = (float*)d_out;

    const size_t HT = (size_t)B_ * H_ * T_ * HD_;   // 8,388,608 elems
    // d_ws (67.1 MB, proven size): [xb|ctx][qh|wob][kh][vT]
    bf16* xb   = (bf16*)d_ws;
    bf16* qh   = xb + HT;
    bf16* kh   = qh + HT;
    bf16* vT   = kh + HT;
    bf16* ctx  = xb;             // xb dead after qkv gemm
    bf16* wob  = qh;             // qh dead after attn
    // d_out (33.55 MB fp32): holds bf16 Wqkv (25.2 MB) until proj overwrites
    bf16* wqkvb = (bf16*)d_out;

    // 1) fp32 -> bf16 pre-convert of x and Wqkv
    convert_xw_kernel<<<2560, 256, 0, stream>>>(x, Wqkv, xb, wqkvb);
    // 2) QKV projection + fused RoPE + head scatter (vT pi-permuted keys)
    qkv_gemm_kernel<<<dim3(48, 32), 256, 0, stream>>>(xb, wqkvb, bqkv, qh, kh, vT);
    // 3) causal flash attention -> ctx: K+V LDS dbuf, no VGPR cap
    attn_kernel<<<1024, 256, 0, stream>>>(qh, kh, vT, ctx);
    // 4) Wo -> bf16 into dead qh region
    convert_wo_kernel<<<1024, 256, 0, stream>>>(Wo, wob);
    // 5) output projection -> fp32 out (overwrites wqkvb region)
    proj_gemm_kernel<<<dim3(16, 32), 256, 0, stream>>>(ctx, wob, bo, out);
}